// Round 7
// baseline (218.083 us; speedup 1.0000x reference)
//
#include <hip/hip_runtime.h>
#include <hip/hip_bf16.h>
#include <stdint.h>

#define HID 128
#define NB 16384
#define TSTEPS 28
#define BN 32

typedef __attribute__((ext_vector_type(8))) short s16x8;
typedef __attribute__((ext_vector_type(4))) float f32x4;

// LDS map: h1 [32][128]bf16 swizzled = 8KB; h0 same = 8KB; xt 2 bufs [32][32]bf16 = 2x2KB
#define H1_OFF 0
#define H0_OFF 8192
#define XT_OFF 16384
#define SMEM_BYTES 20480

__device__ __forceinline__ unsigned int f2bfu(float f) {
  union { float f; uint32_t u; } a; a.f = f;
  uint32_t r = a.u + 0x7FFFu + ((a.u >> 16) & 1u);
  return r >> 16;
}
__device__ __forceinline__ short f2bf(float f) { return (short)f2bfu(f); }
__device__ __forceinline__ unsigned int pack2bf(float lo, float hi) {
  return f2bfu(lo) | (f2bfu(hi) << 16);
}

// h tiles: 256B rows; XOR f(row)=(row^(row>>2))&7 on 16B slots.
__device__ __forceinline__ int swzh(int row, int b) {
  return (row << 8) + (b ^ (((row ^ (row >> 2)) & 7) << 4));
}
// xt tile: 64B rows, 2-bit variant
__device__ __forceinline__ int swzx(int row, int b) {
  return (row << 6) + (b ^ (((row ^ (row >> 2)) & 3) << 4));
}

__device__ __forceinline__ float fsig(float x) {
  float e = __builtin_amdgcn_exp2f(-1.442695041f * x);
  return __builtin_amdgcn_rcpf(1.0f + e);
}
__device__ __forceinline__ float ftanh(float x) {
  float xc = fminf(fmaxf(x, -15.f), 15.f);
  float e = __builtin_amdgcn_exp2f(-2.885390082f * xc);   // e^(-2x)
  float r = __builtin_amdgcn_rcpf(1.0f + e);
  return fmaf(-2.0f * e, r, 1.0f);                        // (1-e)/(1+e)
}

// ---- AGPR-pinned MFMA (R5/R6 post-mortems) ----
// Why asm: 512-thd block -> 256 unified regs/wave; weight frags (108 regs)
// must live on the acc side or the arch side spills to scratch (R4/R5:
// 31-45MB WRITE_SIZE). Why the hazard design: inline-asm MFMA gets NO
// compiler-inserted wait states (R6 failed 0.23 absmax):
//  - SrcC is never VALU-written near use: chains start from zacc, a
//    persistent zero quad pinned in AGPRs at kernel start (biases are
//    added in the fp32 readout instead).
//  - D->C chaining between MFMAs is 0-wait by architecture.
//  - MFMA-write -> VALU(v_accvgpr_read) readout is guarded by one 16-cycle
//    s_nop fence per chain group, tied to the last-written accs.
__device__ __forceinline__ void mfma_first(f32x4& d, const s16x8& a, const s16x8& b,
                                           const f32x4& c0) {
  asm("v_mfma_f32_16x16x32_bf16 %0, %1, %2, %3"
      : "=&a"(d) : "v"(a), "a"(b), "a"(c0));
}
__device__ __forceinline__ void mfma_chain(f32x4& acc, const s16x8& a, const s16x8& b) {
  asm("v_mfma_f32_16x16x32_bf16 %0, %1, %2, %0" : "+a"(acc) : "v"(a), "a"(b));
}
__device__ __forceinline__ void mfma_fence3(f32x4& a0, f32x4& a1, f32x4& a2) {
  asm("s_nop 7\n\ts_nop 7" : "+a"(a0), "+a"(a1), "+a"(a2));
}

__global__ __launch_bounds__(512, 1) void gru_kernel(
    const float* __restrict__ x,
    const float* __restrict__ Wih1, const float* __restrict__ Whh1,
    const float* __restrict__ bih1, const float* __restrict__ bhh1,
    const float* __restrict__ Wih2,
    const float* __restrict__ bih2, const float* __restrict__ bhh2,
    const float* __restrict__ Wout, const float* __restrict__ bout,
    float* __restrict__ out)
{
  __shared__ char smem[SMEM_BYTES];
  const int tid = threadIdx.x;
  const int wv   = tid >> 6;
  const int lane = tid & 63;
  const int l15 = lane & 15;
  const int l16 = lane >> 4;        // 0..3
  const int hc0 = wv * 16;          // this wave's hidden-column slice
  const int n0 = blockIdx.x * BN;

  // ---- persistent zero accumulator quad (pinned in AGPRs, written ONCE) ----
  f32x4 zacc = {0.f, 0.f, 0.f, 0.f};
  asm("" : "+a"(zacc));   // opaque: forces materialization here, no remat near use

  // ---- preload weight B-fragments (forced to AGPRs via "a" constraints) ----
  s16x8 fw_hh1[4][3], fw_ih2[4][3];
  s16x8 fw_ih1[3];
  const int gb0 = hc0, gb1 = 128 + hc0, gb2 = 256 + hc0;
  #pragma unroll
  for (int kf = 0; kf < 4; ++kf) {
    int kbase = kf * 32 + l16 * 8;
    #pragma unroll
    for (int cb = 0; cb < 3; ++cb) {
      int g = (cb == 0 ? gb0 : cb == 1 ? gb1 : gb2) + l15;
      const float* p1 = Whh1 + g * HID + kbase;
      const float* p2 = Wih2 + g * HID + kbase;
      s16x8 f1, f2;
      #pragma unroll
      for (int j = 0; j < 8; ++j) { f1[j] = f2bf(p1[j]); f2[j] = f2bf(p2[j]); }
      fw_hh1[kf][cb] = f1; fw_ih2[kf][cb] = f2;
    }
  }
  {
    int kbase = l16 * 8;
    #pragma unroll
    for (int cb = 0; cb < 3; ++cb) {
      int g = (cb == 0 ? gb0 : cb == 1 ? gb1 : gb2) + l15;
      s16x8 f;
      #pragma unroll
      for (int j = 0; j < 8; ++j) {
        int k = kbase + j;
        f[j] = (k < 28) ? f2bf(Wih1[g * 28 + k]) : (short)0;
      }
      fw_ih1[cb] = f;
    }
  }
  const float b_r  = bih1[gb0 + l15] + bhh1[gb0 + l15];
  const float b_z  = bih1[gb1 + l15] + bhh1[gb1 + l15];
  const float b_ci = bih1[gb2 + l15];
  const float b_ch = bhh1[gb2 + l15];
  const float c_r2 = bih2[gb0 + l15] + bhh2[gb0 + l15];
  const float c_z2 = bih2[gb1 + l15] + bhh2[gb1 + l15];
  const float c_c2 = bih2[gb2 + l15];
  const float c_hc2 = bhh2[gb2 + l15];   // cell2 hc = bhh2_n (h==0)

  float h1reg[2][4];
  #pragma unroll
  for (int rf = 0; rf < 2; ++rf)
    #pragma unroll
    for (int j = 0; j < 4; ++j) h1reg[rf][j] = 0.f;

  // ---- stage xt(0) into buf0 + zero h1 ----
  const int srow = tid >> 4, skp = tid & 15;
  {
    float2 v = make_float2(0.f, 0.f);
    if (skp < 14)
      v = *(const float2*)(x + (size_t)(n0 + srow) * 784 + 2 * skp);
    *(unsigned int*)(smem + XT_OFF + swzx(srow, skp * 4)) = pack2bf(v.x, v.y);
  }
  ((int4*)(smem + H1_OFF))[tid] = make_int4(0, 0, 0, 0);
  __syncthreads();

  #pragma unroll 1
  for (int t = 0; t < TSTEPS; ++t) {
    const int xb = t & 1;
    // ---- cell 1: K = 32 (x) + 128 (h1) ----
    #pragma unroll
    for (int rf = 0; rf < 2; ++rf) {
      int arow = rf * 16 + l15;
      s16x8 ax = *(const s16x8*)(smem + XT_OFF + xb * 2048 + swzx(arow, l16 * 16));
      s16x8 ah[4];
      #pragma unroll
      for (int kf = 0; kf < 4; ++kf)
        ah[kf] = *(const s16x8*)(smem + H1_OFF + swzh(arow, kf * 64 + l16 * 16));
      f32x4 aR, aZ, aCi, aCh;
      mfma_first(aR,  ax, fw_ih1[0], zacc);
      mfma_first(aZ,  ax, fw_ih1[1], zacc);
      mfma_first(aCi, ax, fw_ih1[2], zacc);
      mfma_first(aCh, ah[0], fw_hh1[0][2], zacc);
      #pragma unroll
      for (int kf = 0; kf < 4; ++kf) {
        mfma_chain(aR, ah[kf], fw_hh1[kf][0]);
        mfma_chain(aZ, ah[kf], fw_hh1[kf][1]);
        if (kf > 0) mfma_chain(aCh, ah[kf], fw_hh1[kf][2]);
      }
      mfma_fence3(aR, aZ, aCh);   // MFMA->VALU-read hazard guard
      #pragma unroll
      for (int j = 0; j < 4; ++j) {
        float r = fsig(aR[j] + b_r);
        float z = fsig(aZ[j] + b_z);
        float c = ftanh(fmaf(r, aCh[j] + b_ch, aCi[j] + b_ci));
        float h0 = fmaxf(fmaf(z, h1reg[rf][j] - c, c), 0.f);
        int row = rf * 16 + l16 * 4 + j;
        *(short*)(smem + H0_OFF + swzh(row, (hc0 + l15) << 1)) = f2bf(h0);
      }
    }
    __syncthreads();

    // ---- cell 2 (h==0) + stage xt(t+1) into buf xb^1 ----
    float2 xv = make_float2(0.f, 0.f);
    const bool do_stage = (t + 1 < TSTEPS);
    if (do_stage && skp < 14)
      xv = *(const float2*)(x + (size_t)(n0 + srow) * 784 + (t + 1) * 28 + 2 * skp);
    #pragma unroll
    for (int rf = 0; rf < 2; ++rf) {
      int arow = rf * 16 + l15;
      s16x8 ah[4];
      #pragma unroll
      for (int kf = 0; kf < 4; ++kf)
        ah[kf] = *(const s16x8*)(smem + H0_OFF + swzh(arow, kf * 64 + l16 * 16));
      f32x4 aR, aZ, aC;
      mfma_first(aR, ah[0], fw_ih2[0][0], zacc);
      mfma_first(aZ, ah[0], fw_ih2[0][1], zacc);
      mfma_first(aC, ah[0], fw_ih2[0][2], zacc);
      #pragma unroll
      for (int kf = 1; kf < 4; ++kf) {
        mfma_chain(aR, ah[kf], fw_ih2[kf][0]);
        mfma_chain(aZ, ah[kf], fw_ih2[kf][1]);
        mfma_chain(aC, ah[kf], fw_ih2[kf][2]);
      }
      mfma_fence3(aR, aZ, aC);
      #pragma unroll
      for (int j = 0; j < 4; ++j) {
        float r2 = fsig(aR[j] + c_r2);
        float z2 = fsig(aZ[j] + c_z2);
        float c2 = ftanh(fmaf(r2, c_hc2, aC[j] + c_c2));
        float h1n = c2 - z2 * c2;                 // (1-z2)*c2
        h1reg[rf][j] = h1n;
        int row = rf * 16 + l16 * 4 + j;
        *(short*)(smem + H1_OFF + swzh(row, (hc0 + l15) << 1)) = f2bf(h1n);
      }
    }
    if (do_stage) {
      *(unsigned int*)(smem + XT_OFF + (xb ^ 1) * 2048 + swzx(srow, skp * 4)) =
          pack2bf(xv.x, xv.y);
    }
    __syncthreads();
  }

  // ---- final projection: out = h1 @ Wout^T + bout (fp32 h1 from regs) ----
  float* houtf = (float*)smem;   // [32][132] overlay = 16896 B
  #pragma unroll
  for (int rf = 0; rf < 2; ++rf)
    #pragma unroll
    for (int j = 0; j < 4; ++j) {
      int row = rf * 16 + l16 * 4 + j;
      houtf[row * 132 + hc0 + l15] = h1reg[rf][j];
    }
  __syncthreads();
  if (tid < BN * 10) {
    int row = tid & 31;
    int o = tid >> 5;
    const float* hp = houtf + row * 132;
    const float* wp = Wout + o * HID;
    float s = bout[o];
    #pragma unroll 8
    for (int j2 = 0; j2 < HID; ++j2) s = fmaf(hp[j2], wp[j2], s);
    out[(size_t)(n0 + row) * 10 + o] = s;
  }
}

extern "C" void kernel_launch(void* const* d_in, const int* in_sizes, int n_in,
                              void* d_out, int out_size, void* d_ws, size_t ws_size,
                              hipStream_t stream) {
  const float* x    = (const float*)d_in[0];
  const float* Wih1 = (const float*)d_in[1];
  const float* Whh1 = (const float*)d_in[2];
  const float* bih1 = (const float*)d_in[3];
  const float* bhh1 = (const float*)d_in[4];
  const float* Wih2 = (const float*)d_in[5];
  // d_in[6] = Whh2: multiplied by zero hidden state in the reference -> unused
  const float* bih2 = (const float*)d_in[7];
  const float* bhh2 = (const float*)d_in[8];
  const float* Wout = (const float*)d_in[9];
  const float* bout = (const float*)d_in[10];
  gru_kernel<<<NB / BN, 512, 0, stream>>>(x, Wih1, Whh1, bih1, bhh1,
                                          Wih2, bih2, bhh2, Wout, bout,
                                          (float*)d_out);
}

// Round 8
// 215.889 us; speedup vs baseline: 1.0102x; 1.0102x over previous
//
#include <hip/hip_runtime.h>
#include <hip/hip_bf16.h>
#include <stdint.h>

#define HID 128
#define NB 16384
#define TSTEPS 28
#define BN 32

typedef __attribute__((ext_vector_type(8))) short s16x8;
typedef __attribute__((ext_vector_type(4))) float f32x4;

// LDS map: h1 [32][128]bf16 swizzled = 8KB; h0 same = 8KB; xt 2 bufs [32][32]bf16 = 2x2KB
#define H1_OFF 0
#define H0_OFF 8192
#define XT_OFF 16384
#define SMEM_BYTES 20480

__device__ __forceinline__ unsigned int f2bfu(float f) {
  union { float f; uint32_t u; } a; a.f = f;
  uint32_t r = a.u + 0x7FFFu + ((a.u >> 16) & 1u);
  return r >> 16;
}
__device__ __forceinline__ short f2bf(float f) { return (short)f2bfu(f); }
__device__ __forceinline__ unsigned int pack2bf(float lo, float hi) {
  return f2bfu(lo) | (f2bfu(hi) << 16);
}

// h tiles: 256B rows; XOR f(row)=(row^(row>>2))&7 on 16B slots.
__device__ __forceinline__ int swzh(int row, int b) {
  return (row << 8) + (b ^ (((row ^ (row >> 2)) & 7) << 4));
}
// xt tile: 64B rows, 2-bit variant
__device__ __forceinline__ int swzx(int row, int b) {
  return (row << 6) + (b ^ (((row ^ (row >> 2)) & 3) << 4));
}

__device__ __forceinline__ float fsig(float x) {
  float e = __builtin_amdgcn_exp2f(-1.442695041f * x);
  return __builtin_amdgcn_rcpf(1.0f + e);
}
__device__ __forceinline__ float ftanh(float x) {
  float xc = fminf(fmaxf(x, -15.f), 15.f);
  float e = __builtin_amdgcn_exp2f(-2.885390082f * xc);   // e^(-2x)
  float r = __builtin_amdgcn_rcpf(1.0f + e);
  return fmaf(-2.0f * e, r, 1.0f);                        // (1-e)/(1+e)
}

// ---- Register-budget ledger (R4..R7 post-mortems) ----
// 512-thd block -> 256 unified regs/wave, compiler splits 128 arch + 128 acc.
// R5 (all weights VGPR): arch demand ~170 -> 30-dword spill (31MB scratch).
// R7 (ALL weights+zacc+accs AGPR): acc side = exactly 128, zero slack ->
//   allocator cascade-spilled WORSE (82MB). Lesson: leave slack on BOTH sides.
// R8 split: AGPR = fw_hh1(48) + fw_ih2(48) + zacc(4) + live accs(16) = 116.
//           VGPR = fw_ih1(12) + biases(8) + h1reg(8) + A-frags(20) + addr ~76.
// Hazard design (proven correct in R7, absmax 4.88e-4):
//  - chains seeded from zacc (persistent AGPR zero quad, written once at init,
//    far from first use) -> no VALU->MFMA SrcC hazard;
//  - D->C accumulate chaining is 0-wait for same-type XDL ops;
//  - one 16-cycle s_nop fence per chain group before the VALU readout.
__device__ __forceinline__ void mfma_first_vb(f32x4& d, const s16x8& a, const s16x8& b,
                                              const f32x4& c0) {
  asm("v_mfma_f32_16x16x32_bf16 %0, %1, %2, %3"
      : "=&a"(d) : "v"(a), "v"(b), "a"(c0));
}
__device__ __forceinline__ void mfma_first_ab(f32x4& d, const s16x8& a, const s16x8& b,
                                              const f32x4& c0) {
  asm("v_mfma_f32_16x16x32_bf16 %0, %1, %2, %3"
      : "=&a"(d) : "v"(a), "a"(b), "a"(c0));
}
__device__ __forceinline__ void mfma_chain_ab(f32x4& acc, const s16x8& a, const s16x8& b) {
  asm("v_mfma_f32_16x16x32_bf16 %0, %1, %2, %0" : "+a"(acc) : "v"(a), "a"(b));
}
__device__ __forceinline__ void mfma_fence3(f32x4& a0, f32x4& a1, f32x4& a2) {
  asm("s_nop 7\n\ts_nop 7" : "+a"(a0), "+a"(a1), "+a"(a2));
}

__global__ __launch_bounds__(512, 1) void gru_kernel(
    const float* __restrict__ x,
    const float* __restrict__ Wih1, const float* __restrict__ Whh1,
    const float* __restrict__ bih1, const float* __restrict__ bhh1,
    const float* __restrict__ Wih2,
    const float* __restrict__ bih2, const float* __restrict__ bhh2,
    const float* __restrict__ Wout, const float* __restrict__ bout,
    float* __restrict__ out)
{
  __shared__ char smem[SMEM_BYTES];
  const int tid = threadIdx.x;
  const int wv   = tid >> 6;
  const int lane = tid & 63;
  const int l15 = lane & 15;
  const int l16 = lane >> 4;        // 0..3
  const int hc0 = wv * 16;          // this wave's hidden-column slice
  const int n0 = blockIdx.x * BN;

  // ---- persistent zero accumulator quad (pinned in AGPRs, written ONCE) ----
  f32x4 zacc = {0.f, 0.f, 0.f, 0.f};
  asm("" : "+a"(zacc));   // opaque: forces materialization here, no remat near use

  // ---- preload weight B-fragments ----
  // fw_hh1 / fw_ih2 live in AGPRs (via "a" asm constraints); fw_ih1 in VGPRs.
  s16x8 fw_hh1[4][3], fw_ih2[4][3];
  s16x8 fw_ih1[3];
  const int gb0 = hc0, gb1 = 128 + hc0, gb2 = 256 + hc0;
  #pragma unroll
  for (int kf = 0; kf < 4; ++kf) {
    int kbase = kf * 32 + l16 * 8;
    #pragma unroll
    for (int cb = 0; cb < 3; ++cb) {
      int g = (cb == 0 ? gb0 : cb == 1 ? gb1 : gb2) + l15;
      const float* p1 = Whh1 + g * HID + kbase;
      const float* p2 = Wih2 + g * HID + kbase;
      s16x8 f1, f2;
      #pragma unroll
      for (int j = 0; j < 8; ++j) { f1[j] = f2bf(p1[j]); f2[j] = f2bf(p2[j]); }
      fw_hh1[kf][cb] = f1; fw_ih2[kf][cb] = f2;
    }
  }
  {
    int kbase = l16 * 8;
    #pragma unroll
    for (int cb = 0; cb < 3; ++cb) {
      int g = (cb == 0 ? gb0 : cb == 1 ? gb1 : gb2) + l15;
      s16x8 f;
      #pragma unroll
      for (int j = 0; j < 8; ++j) {
        int k = kbase + j;
        f[j] = (k < 28) ? f2bf(Wih1[g * 28 + k]) : (short)0;
      }
      fw_ih1[cb] = f;
    }
  }
  const float b_r  = bih1[gb0 + l15] + bhh1[gb0 + l15];
  const float b_z  = bih1[gb1 + l15] + bhh1[gb1 + l15];
  const float b_ci = bih1[gb2 + l15];
  const float b_ch = bhh1[gb2 + l15];
  const float c_r2 = bih2[gb0 + l15] + bhh2[gb0 + l15];
  const float c_z2 = bih2[gb1 + l15] + bhh2[gb1 + l15];
  const float c_c2 = bih2[gb2 + l15];
  const float c_hc2 = bhh2[gb2 + l15];   // cell2 hc = bhh2_n (h==0)

  float h1reg[2][4];
  #pragma unroll
  for (int rf = 0; rf < 2; ++rf)
    #pragma unroll
    for (int j = 0; j < 4; ++j) h1reg[rf][j] = 0.f;

  // ---- stage xt(0) into buf0 + zero h1 ----
  const int srow = tid >> 4, skp = tid & 15;
  {
    float2 v = make_float2(0.f, 0.f);
    if (skp < 14)
      v = *(const float2*)(x + (size_t)(n0 + srow) * 784 + 2 * skp);
    *(unsigned int*)(smem + XT_OFF + swzx(srow, skp * 4)) = pack2bf(v.x, v.y);
  }
  ((int4*)(smem + H1_OFF))[tid] = make_int4(0, 0, 0, 0);
  __syncthreads();

  #pragma unroll 1
  for (int t = 0; t < TSTEPS; ++t) {
    const int xb = t & 1;
    // ---- cell 1: K = 32 (x) + 128 (h1) ----
    #pragma unroll
    for (int rf = 0; rf < 2; ++rf) {
      int arow = rf * 16 + l15;
      s16x8 ax = *(const s16x8*)(smem + XT_OFF + xb * 2048 + swzx(arow, l16 * 16));
      s16x8 ah[4];
      #pragma unroll
      for (int kf = 0; kf < 4; ++kf)
        ah[kf] = *(const s16x8*)(smem + H1_OFF + swzh(arow, kf * 64 + l16 * 16));
      f32x4 aR, aZ, aCi, aCh;
      mfma_first_vb(aCi, ax, fw_ih1[2], zacc);   // written early, read late
      mfma_first_vb(aR,  ax, fw_ih1[0], zacc);
      mfma_first_vb(aZ,  ax, fw_ih1[1], zacc);
      mfma_first_ab(aCh, ah[0], fw_hh1[0][2], zacc);
      #pragma unroll
      for (int kf = 0; kf < 4; ++kf) {
        mfma_chain_ab(aR, ah[kf], fw_hh1[kf][0]);
        mfma_chain_ab(aZ, ah[kf], fw_hh1[kf][1]);
        if (kf > 0) mfma_chain_ab(aCh, ah[kf], fw_hh1[kf][2]);
      }
      mfma_fence3(aR, aZ, aCh);   // MFMA->VALU-read hazard guard
      #pragma unroll
      for (int j = 0; j < 4; ++j) {
        float r = fsig(aR[j] + b_r);
        float z = fsig(aZ[j] + b_z);
        float c = ftanh(fmaf(r, aCh[j] + b_ch, aCi[j] + b_ci));
        float h0 = fmaxf(fmaf(z, h1reg[rf][j] - c, c), 0.f);
        int row = rf * 16 + l16 * 4 + j;
        *(short*)(smem + H0_OFF + swzh(row, (hc0 + l15) << 1)) = f2bf(h0);
      }
    }
    __syncthreads();

    // ---- cell 2 (h==0) + stage xt(t+1) into buf xb^1 ----
    float2 xv = make_float2(0.f, 0.f);
    const bool do_stage = (t + 1 < TSTEPS);
    if (do_stage && skp < 14)
      xv = *(const float2*)(x + (size_t)(n0 + srow) * 784 + (t + 1) * 28 + 2 * skp);
    #pragma unroll
    for (int rf = 0; rf < 2; ++rf) {
      int arow = rf * 16 + l15;
      s16x8 ah[4];
      #pragma unroll
      for (int kf = 0; kf < 4; ++kf)
        ah[kf] = *(const s16x8*)(smem + H0_OFF + swzh(arow, kf * 64 + l16 * 16));
      f32x4 aR, aZ, aC;
      mfma_first_ab(aR, ah[0], fw_ih2[0][0], zacc);
      mfma_first_ab(aZ, ah[0], fw_ih2[0][1], zacc);
      mfma_first_ab(aC, ah[0], fw_ih2[0][2], zacc);
      #pragma unroll
      for (int kf = 1; kf < 4; ++kf) {
        mfma_chain_ab(aR, ah[kf], fw_ih2[kf][0]);
        mfma_chain_ab(aZ, ah[kf], fw_ih2[kf][1]);
        mfma_chain_ab(aC, ah[kf], fw_ih2[kf][2]);
      }
      mfma_fence3(aR, aZ, aC);
      #pragma unroll
      for (int j = 0; j < 4; ++j) {
        float r2 = fsig(aR[j] + c_r2);
        float z2 = fsig(aZ[j] + c_z2);
        float c2 = ftanh(fmaf(r2, c_hc2, aC[j] + c_c2));
        float h1n = c2 - z2 * c2;                 // (1-z2)*c2
        h1reg[rf][j] = h1n;
        int row = rf * 16 + l16 * 4 + j;
        *(short*)(smem + H1_OFF + swzh(row, (hc0 + l15) << 1)) = f2bf(h1n);
      }
    }
    if (do_stage) {
      *(unsigned int*)(smem + XT_OFF + (xb ^ 1) * 2048 + swzx(srow, skp * 4)) =
          pack2bf(xv.x, xv.y);
    }
    __syncthreads();
  }

  // ---- final projection: out = h1 @ Wout^T + bout (fp32 h1 from regs) ----
  float* houtf = (float*)smem;   // [32][132] overlay = 16896 B
  #pragma unroll
  for (int rf = 0; rf < 2; ++rf)
    #pragma unroll
    for (int j = 0; j < 4; ++j) {
      int row = rf * 16 + l16 * 4 + j;
      houtf[row * 132 + hc0 + l15] = h1reg[rf][j];
    }
  __syncthreads();
  if (tid < BN * 10) {
    int row = tid & 31;
    int o = tid >> 5;
    const float* hp = houtf + row * 132;
    const float* wp = Wout + o * HID;
    float s = bout[o];
    #pragma unroll 8
    for (int j2 = 0; j2 < HID; ++j2) s = fmaf(hp[j2], wp[j2], s);
    out[(size_t)(n0 + row) * 10 + o] = s;
  }
}

extern "C" void kernel_launch(void* const* d_in, const int* in_sizes, int n_in,
                              void* d_out, int out_size, void* d_ws, size_t ws_size,
                              hipStream_t stream) {
  const float* x    = (const float*)d_in[0];
  const float* Wih1 = (const float*)d_in[1];
  const float* Whh1 = (const float*)d_in[2];
  const float* bih1 = (const float*)d_in[3];
  const float* bhh1 = (const float*)d_in[4];
  const float* Wih2 = (const float*)d_in[5];
  // d_in[6] = Whh2: multiplied by zero hidden state in the reference -> unused
  const float* bih2 = (const float*)d_in[7];
  const float* bhh2 = (const float*)d_in[8];
  const float* Wout = (const float*)d_in[9];
  const float* bout = (const float*)d_in[10];
  gru_kernel<<<NB / BN, 512, 0, stream>>>(x, Wih1, Whh1, bih1, bhh1,
                                          Wih2, bih2, bhh2, Wout, bout,
                                          (float*)d_out);
}

// Round 9
// 172.719 us; speedup vs baseline: 1.2626x; 1.2499x over previous
//
#include <hip/hip_runtime.h>
#include <hip/hip_bf16.h>
#include <stdint.h>

#define HID 128
#define NB 16384
#define TSTEPS 28
#define BN 32

typedef __attribute__((ext_vector_type(8))) short s16x8;
typedef __attribute__((ext_vector_type(4))) float f32x4;

// LDS map:
//   H1 tile [32][128]bf16 swizzled   8KB  @ 0
//   H0 tile                          8KB  @ 8192
//   XT 2 bufs [32][32]bf16           4KB  @ 16384
//   WI2 frags [8 wv][4 kf][3 cb][64 lane][16B] = 96KB @ 20480
// Total 118784 B (< 160KB/CU; >64KB static LDS works on gfx950 per m201).
#define H1_OFF 0
#define H0_OFF 8192
#define XT_OFF 16384
#define WI2_OFF 20480
#define SMEM_BYTES 118784

__device__ __forceinline__ unsigned int f2bfu(float f) {
  union { float f; uint32_t u; } a; a.f = f;
  uint32_t r = a.u + 0x7FFFu + ((a.u >> 16) & 1u);
  return r >> 16;
}
__device__ __forceinline__ short f2bf(float f) { return (short)f2bfu(f); }
__device__ __forceinline__ unsigned int pack2bf(float lo, float hi) {
  return f2bfu(lo) | (f2bfu(hi) << 16);
}

// h tiles: 256B rows; XOR f(row)=(row^(row>>2))&7 on 16B slots.
__device__ __forceinline__ int swzh(int row, int b) {
  return (row << 8) + (b ^ (((row ^ (row >> 2)) & 7) << 4));
}
// xt tile: 64B rows, 2-bit variant
__device__ __forceinline__ int swzx(int row, int b) {
  return (row << 6) + (b ^ (((row ^ (row >> 2)) & 3) << 4));
}

__device__ __forceinline__ float fsig(float x) {
  float e = __builtin_amdgcn_exp2f(-1.442695041f * x);
  return __builtin_amdgcn_rcpf(1.0f + e);
}
__device__ __forceinline__ float ftanh(float x) {
  float xc = fminf(fmaxf(x, -15.f), 15.f);
  float e = __builtin_amdgcn_exp2f(-2.885390082f * xc);   // e^(-2x)
  float r = __builtin_amdgcn_rcpf(1.0f + e);
  return fmaf(-2.0f * e, r, 1.0f);                        // (1-e)/(1+e)
}

// ---- Register-budget ledger (R3..R8 post-mortems) ----
// 512-thd block -> 256 unified regs/wave, split 128 arch + 128 acc.
// All-weights-in-regs needs ~150-170 arch -> unavoidable spill (R5: 31MB,
// R7/R8 asm AGPR-pinning: worse, 71-82MB — allocator copies around asm).
// R9: Wih2 frags (48 regs) -> LDS, read once/step shared across both rf.
// Persistent arch: fw_hh1 48 + fw_ih1 12 + biases 8 + h1reg 8 + addr ~10
// = ~86; peak with transients ~116 <= 128 -> no spill, pure intrinsics.
__global__ __launch_bounds__(512, 1) void gru_kernel(
    const float* __restrict__ x,
    const float* __restrict__ Wih1, const float* __restrict__ Whh1,
    const float* __restrict__ bih1, const float* __restrict__ bhh1,
    const float* __restrict__ Wih2,
    const float* __restrict__ bih2, const float* __restrict__ bhh2,
    const float* __restrict__ Wout, const float* __restrict__ bout,
    float* __restrict__ out)
{
  __shared__ char smem[SMEM_BYTES];
  const int tid = threadIdx.x;
  const int wv   = tid >> 6;
  const int lane = tid & 63;
  const int l15 = lane & 15;
  const int l16 = lane >> 4;        // 0..3
  const int hc0 = wv * 16;          // this wave's hidden-column slice
  const int n0 = blockIdx.x * BN;

  // ---- preload weights ----
  // fw_hh1 / fw_ih1 stay in VGPRs; Wih2 frags go to LDS (per-wave layout).
  s16x8 fw_hh1[4][3];
  s16x8 fw_ih1[3];
  const int gb0 = hc0, gb1 = 128 + hc0, gb2 = 256 + hc0;
  #pragma unroll
  for (int kf = 0; kf < 4; ++kf) {
    int kbase = kf * 32 + l16 * 8;
    #pragma unroll
    for (int cb = 0; cb < 3; ++cb) {
      int g = (cb == 0 ? gb0 : cb == 1 ? gb1 : gb2) + l15;
      const float* p1 = Whh1 + g * HID + kbase;
      const float* p2 = Wih2 + g * HID + kbase;
      s16x8 f1, f2;
      #pragma unroll
      for (int j = 0; j < 8; ++j) { f1[j] = f2bf(p1[j]); f2[j] = f2bf(p2[j]); }
      fw_hh1[kf][cb] = f1;
      // LDS frag slot: [wv][kf][cb] x 1KB, lane*16 within
      *(s16x8*)(smem + WI2_OFF + ((wv * 12 + kf * 3 + cb) << 10) + lane * 16) = f2;
    }
  }
  {
    int kbase = l16 * 8;
    #pragma unroll
    for (int cb = 0; cb < 3; ++cb) {
      int g = (cb == 0 ? gb0 : cb == 1 ? gb1 : gb2) + l15;
      s16x8 f;
      #pragma unroll
      for (int j = 0; j < 8; ++j) {
        int k = kbase + j;
        f[j] = (k < 28) ? f2bf(Wih1[g * 28 + k]) : (short)0;
      }
      fw_ih1[cb] = f;
    }
  }
  const float b_r  = bih1[gb0 + l15] + bhh1[gb0 + l15];
  const float b_z  = bih1[gb1 + l15] + bhh1[gb1 + l15];
  const float b_ci = bih1[gb2 + l15];
  const float b_ch = bhh1[gb2 + l15];
  const float c_r2 = bih2[gb0 + l15] + bhh2[gb0 + l15];
  const float c_z2 = bih2[gb1 + l15] + bhh2[gb1 + l15];
  const float c_c2 = bih2[gb2 + l15];
  const float c_hc2 = bhh2[gb2 + l15];   // cell2 hc = bhh2_n (h==0)

  float h1reg[2][4];
  #pragma unroll
  for (int rf = 0; rf < 2; ++rf)
    #pragma unroll
    for (int j = 0; j < 4; ++j) h1reg[rf][j] = 0.f;

  // ---- stage xt(0) into buf0 + zero h1 ----
  const int srow = tid >> 4, skp = tid & 15;
  {
    float2 v = make_float2(0.f, 0.f);
    if (skp < 14)
      v = *(const float2*)(x + (size_t)(n0 + srow) * 784 + 2 * skp);
    *(unsigned int*)(smem + XT_OFF + swzx(srow, skp * 4)) = pack2bf(v.x, v.y);
  }
  ((int4*)(smem + H1_OFF))[tid] = make_int4(0, 0, 0, 0);
  __syncthreads();

  #pragma unroll 1
  for (int t = 0; t < TSTEPS; ++t) {
    const int xb = t & 1;
    // ---- cell 1: K = 32 (x) + 128 (h1); B-frags from VGPRs ----
    #pragma unroll
    for (int rf = 0; rf < 2; ++rf) {
      int arow = rf * 16 + l15;
      s16x8 ax = *(const s16x8*)(smem + XT_OFF + xb * 2048 + swzx(arow, l16 * 16));
      s16x8 ah[4];
      #pragma unroll
      for (int kf = 0; kf < 4; ++kf)
        ah[kf] = *(const s16x8*)(smem + H1_OFF + swzh(arow, kf * 64 + l16 * 16));
      f32x4 aR  = {b_r,  b_r,  b_r,  b_r };
      f32x4 aZ  = {b_z,  b_z,  b_z,  b_z };
      f32x4 aCi = {b_ci, b_ci, b_ci, b_ci};
      f32x4 aCh = {b_ch, b_ch, b_ch, b_ch};
      aR  = __builtin_amdgcn_mfma_f32_16x16x32_bf16(ax, fw_ih1[0], aR, 0, 0, 0);
      aZ  = __builtin_amdgcn_mfma_f32_16x16x32_bf16(ax, fw_ih1[1], aZ, 0, 0, 0);
      aCi = __builtin_amdgcn_mfma_f32_16x16x32_bf16(ax, fw_ih1[2], aCi, 0, 0, 0);
      #pragma unroll
      for (int kf = 0; kf < 4; ++kf) {
        aR  = __builtin_amdgcn_mfma_f32_16x16x32_bf16(ah[kf], fw_hh1[kf][0], aR, 0, 0, 0);
        aZ  = __builtin_amdgcn_mfma_f32_16x16x32_bf16(ah[kf], fw_hh1[kf][1], aZ, 0, 0, 0);
        aCh = __builtin_amdgcn_mfma_f32_16x16x32_bf16(ah[kf], fw_hh1[kf][2], aCh, 0, 0, 0);
      }
      #pragma unroll
      for (int j = 0; j < 4; ++j) {
        float r = fsig(aR[j]);
        float z = fsig(aZ[j]);
        float c = ftanh(fmaf(r, aCh[j], aCi[j]));
        float h0 = fmaxf(fmaf(z, h1reg[rf][j] - c, c), 0.f);
        int row = rf * 16 + l16 * 4 + j;
        *(short*)(smem + H0_OFF + swzh(row, (hc0 + l15) << 1)) = f2bf(h0);
      }
    }
    __syncthreads();

    // ---- cell 2 (h==0): B-frags from LDS, shared across both rf ----
    float2 xv = make_float2(0.f, 0.f);
    const bool do_stage = (t + 1 < TSTEPS);
    if (do_stage && skp < 14)
      xv = *(const float2*)(x + (size_t)(n0 + srow) * 784 + (t + 1) * 28 + 2 * skp);
    {
      f32x4 aR2[2], aZ2[2], aC2[2];
      #pragma unroll
      for (int rf = 0; rf < 2; ++rf) {
        aR2[rf] = (f32x4){c_r2, c_r2, c_r2, c_r2};
        aZ2[rf] = (f32x4){c_z2, c_z2, c_z2, c_z2};
        aC2[rf] = (f32x4){c_c2, c_c2, c_c2, c_c2};
      }
      #pragma unroll
      for (int kf = 0; kf < 4; ++kf) {
        s16x8 a0 = *(const s16x8*)(smem + H0_OFF + swzh(l15,      kf * 64 + l16 * 16));
        s16x8 a1 = *(const s16x8*)(smem + H0_OFF + swzh(16 + l15, kf * 64 + l16 * 16));
        const char* wb = smem + WI2_OFF + ((wv * 12 + kf * 3) << 10) + lane * 16;
        s16x8 b0 = *(const s16x8*)(wb);
        s16x8 b1 = *(const s16x8*)(wb + 1024);
        s16x8 b2 = *(const s16x8*)(wb + 2048);
        aR2[0] = __builtin_amdgcn_mfma_f32_16x16x32_bf16(a0, b0, aR2[0], 0, 0, 0);
        aR2[1] = __builtin_amdgcn_mfma_f32_16x16x32_bf16(a1, b0, aR2[1], 0, 0, 0);
        aZ2[0] = __builtin_amdgcn_mfma_f32_16x16x32_bf16(a0, b1, aZ2[0], 0, 0, 0);
        aZ2[1] = __builtin_amdgcn_mfma_f32_16x16x32_bf16(a1, b1, aZ2[1], 0, 0, 0);
        aC2[0] = __builtin_amdgcn_mfma_f32_16x16x32_bf16(a0, b2, aC2[0], 0, 0, 0);
        aC2[1] = __builtin_amdgcn_mfma_f32_16x16x32_bf16(a1, b2, aC2[1], 0, 0, 0);
      }
      #pragma unroll
      for (int rf = 0; rf < 2; ++rf)
        #pragma unroll
        for (int j = 0; j < 4; ++j) {
          float r2 = fsig(aR2[rf][j]);
          float z2 = fsig(aZ2[rf][j]);
          float c2 = ftanh(fmaf(r2, c_hc2, aC2[rf][j]));
          float h1n = c2 - z2 * c2;                 // (1-z2)*c2
          h1reg[rf][j] = h1n;
          int row = rf * 16 + l16 * 4 + j;
          *(short*)(smem + H1_OFF + swzh(row, (hc0 + l15) << 1)) = f2bf(h1n);
        }
    }
    if (do_stage) {
      *(unsigned int*)(smem + XT_OFF + (xb ^ 1) * 2048 + swzx(srow, skp * 4)) =
          pack2bf(xv.x, xv.y);
    }
    __syncthreads();
  }

  // ---- final projection: out = h1 @ Wout^T + bout (fp32 h1 from regs) ----
  float* houtf = (float*)smem;   // [32][132] overlay = 16896 B
  #pragma unroll
  for (int rf = 0; rf < 2; ++rf)
    #pragma unroll
    for (int j = 0; j < 4; ++j) {
      int row = rf * 16 + l16 * 4 + j;
      houtf[row * 132 + hc0 + l15] = h1reg[rf][j];
    }
  __syncthreads();
  if (tid < BN * 10) {
    int row = tid & 31;
    int o = tid >> 5;
    const float* hp = houtf + row * 132;
    const float* wp = Wout + o * HID;
    float s = bout[o];
    #pragma unroll 8
    for (int j2 = 0; j2 < HID; ++j2) s = fmaf(hp[j2], wp[j2], s);
    out[(size_t)(n0 + row) * 10 + o] = s;
  }
}

extern "C" void kernel_launch(void* const* d_in, const int* in_sizes, int n_in,
                              void* d_out, int out_size, void* d_ws, size_t ws_size,
                              hipStream_t stream) {
  const float* x    = (const float*)d_in[0];
  const float* Wih1 = (const float*)d_in[1];
  const float* Whh1 = (const float*)d_in[2];
  const float* bih1 = (const float*)d_in[3];
  const float* bhh1 = (const float*)d_in[4];
  const float* Wih2 = (const float*)d_in[5];
  // d_in[6] = Whh2: multiplied by zero hidden state in the reference -> unused
  const float* bih2 = (const float*)d_in[7];
  const float* bhh2 = (const float*)d_in[8];
  const float* Wout = (const float*)d_in[9];
  const float* bout = (const float*)d_in[10];
  gru_kernel<<<NB / BN, 512, 0, stream>>>(x, Wih1, Whh1, bih1, bhh1,
                                          Wih2, bih2, bhh2, Wout, bout,
                                          (float*)d_out);
}

// Round 10
// 153.023 us; speedup vs baseline: 1.4252x; 1.1287x over previous
//
#include <hip/hip_runtime.h>
#include <hip/hip_bf16.h>
#include <stdint.h>

#define HID 128
#define NB 16384
#define TSTEPS 28
#define BN 64

typedef __attribute__((ext_vector_type(8))) short s16x8;
typedef __attribute__((ext_vector_type(4))) float f32x4;

// LDS map (136 KB total -> 1 block/CU, structural):
//   H1 tile [64][128]bf16 swizzled   16KB @ 0
//   H0 tile                          16KB @ 16384
//   XT 2 bufs [64][32]bf16           2x4KB @ 32768
//   WI2 frags [8 wv][4 kf][3 cb][64 lane][16B] = 96KB @ 40960
#define H1_OFF 0
#define H0_OFF 16384
#define XT_OFF 32768
#define WI2_OFF 40960
#define SMEM_BYTES 139264

__device__ __forceinline__ unsigned int f2bfu(float f) {
  union { float f; uint32_t u; } a; a.f = f;
  uint32_t r = a.u + 0x7FFFu + ((a.u >> 16) & 1u);
  return r >> 16;
}
__device__ __forceinline__ short f2bf(float f) { return (short)f2bfu(f); }
__device__ __forceinline__ unsigned int pack2bf(float lo, float hi) {
  return f2bfu(lo) | (f2bfu(hi) << 16);
}

// h tiles: 256B rows; XOR f(row)=(row^(row>>2))&7 on 16B slots.
// Injective on the write quads {4a..4a+3}, 2-regular on 16-row reads.
__device__ __forceinline__ int swzh(int row, int b) {
  return (row << 8) + (b ^ (((row ^ (row >> 2)) & 7) << 4));
}
// xt tile: 64B rows, 2-bit variant
__device__ __forceinline__ int swzx(int row, int b) {
  return (row << 6) + (b ^ (((row ^ (row >> 2)) & 3) << 4));
}

__device__ __forceinline__ float fsig(float x) {
  float e = __builtin_amdgcn_exp2f(-1.442695041f * x);
  return __builtin_amdgcn_rcpf(1.0f + e);
}
__device__ __forceinline__ float ftanh(float x) {
  float xc = fminf(fmaxf(x, -15.f), 15.f);
  float e = __builtin_amdgcn_exp2f(-2.885390082f * xc);   // e^(-2x)
  float r = __builtin_amdgcn_rcpf(1.0f + e);
  return fmaf(-2.0f * e, r, 1.0f);                        // (1-e)/(1+e)
}

// ---- Design ledger (R3..R9) ----
// 512-thd block: 256 unified regs/wave. All-weights-in-regs (~150-170 arch)
// spills (R5/R7/R8). R9 (Wih2->LDS, pure intrinsics): no spill, VGPR=108,
// but LDS 119KB -> 1 block/CU, 512 blocks -> 56 serial barrier-steps/CU,
// latency-bound at 2 waves/SIMD. R10: BN=64 -> 256 blocks -> 28 steps/CU,
// doubled per-step ILP (4 independent rf chains) fills the same latency.
// Cell2 processes rf pairs sharing LDS B-frags to keep peak pressure ~R9.
__global__ __launch_bounds__(512, 1) void gru_kernel(
    const float* __restrict__ x,
    const float* __restrict__ Wih1, const float* __restrict__ Whh1,
    const float* __restrict__ bih1, const float* __restrict__ bhh1,
    const float* __restrict__ Wih2,
    const float* __restrict__ bih2, const float* __restrict__ bhh2,
    const float* __restrict__ Wout, const float* __restrict__ bout,
    float* __restrict__ out)
{
  __shared__ char smem[SMEM_BYTES];
  const int tid = threadIdx.x;
  const int wv   = tid >> 6;
  const int lane = tid & 63;
  const int l15 = lane & 15;
  const int l16 = lane >> 4;        // 0..3
  const int hc0 = wv * 16;          // this wave's hidden-column slice
  const int n0 = blockIdx.x * BN;

  // ---- preload weights: fw_hh1/fw_ih1 in VGPRs; Wih2 frags -> LDS ----
  s16x8 fw_hh1[4][3];
  s16x8 fw_ih1[3];
  const int gb0 = hc0, gb1 = 128 + hc0, gb2 = 256 + hc0;
  #pragma unroll
  for (int kf = 0; kf < 4; ++kf) {
    int kbase = kf * 32 + l16 * 8;
    #pragma unroll
    for (int cb = 0; cb < 3; ++cb) {
      int g = (cb == 0 ? gb0 : cb == 1 ? gb1 : gb2) + l15;
      const float* p1 = Whh1 + g * HID + kbase;
      const float* p2 = Wih2 + g * HID + kbase;
      s16x8 f1, f2;
      #pragma unroll
      for (int j = 0; j < 8; ++j) { f1[j] = f2bf(p1[j]); f2[j] = f2bf(p2[j]); }
      fw_hh1[kf][cb] = f1;
      *(s16x8*)(smem + WI2_OFF + ((wv * 12 + kf * 3 + cb) << 10) + lane * 16) = f2;
    }
  }
  {
    int kbase = l16 * 8;
    #pragma unroll
    for (int cb = 0; cb < 3; ++cb) {
      int g = (cb == 0 ? gb0 : cb == 1 ? gb1 : gb2) + l15;
      s16x8 f;
      #pragma unroll
      for (int j = 0; j < 8; ++j) {
        int k = kbase + j;
        f[j] = (k < 28) ? f2bf(Wih1[g * 28 + k]) : (short)0;
      }
      fw_ih1[cb] = f;
    }
  }
  const float b_r  = bih1[gb0 + l15] + bhh1[gb0 + l15];
  const float b_z  = bih1[gb1 + l15] + bhh1[gb1 + l15];
  const float b_ci = bih1[gb2 + l15];
  const float b_ch = bhh1[gb2 + l15];
  const float c_r2 = bih2[gb0 + l15] + bhh2[gb0 + l15];
  const float c_z2 = bih2[gb1 + l15] + bhh2[gb1 + l15];
  const float c_c2 = bih2[gb2 + l15];
  const float c_hc2 = bhh2[gb2 + l15];   // cell2 hc = bhh2_n (h==0)

  float h1reg[4][4];
  #pragma unroll
  for (int rf = 0; rf < 4; ++rf)
    #pragma unroll
    for (int j = 0; j < 4; ++j) h1reg[rf][j] = 0.f;

  // ---- stage xt(0) into buf0 + zero h1 ----
  const int srow = tid >> 4, skp = tid & 15;   // slot 0; slot 1 = row+32
  {
    float2 v0 = make_float2(0.f, 0.f), v1 = make_float2(0.f, 0.f);
    if (skp < 14) {
      v0 = *(const float2*)(x + (size_t)(n0 + srow) * 784 + 2 * skp);
      v1 = *(const float2*)(x + (size_t)(n0 + srow + 32) * 784 + 2 * skp);
    }
    *(unsigned int*)(smem + XT_OFF + swzx(srow, skp * 4))      = pack2bf(v0.x, v0.y);
    *(unsigned int*)(smem + XT_OFF + swzx(srow + 32, skp * 4)) = pack2bf(v1.x, v1.y);
  }
  ((int4*)(smem + H1_OFF))[tid] = make_int4(0, 0, 0, 0);
  ((int4*)(smem + H1_OFF))[tid + 512] = make_int4(0, 0, 0, 0);
  __syncthreads();

  #pragma unroll 1
  for (int t = 0; t < TSTEPS; ++t) {
    const int xb = t & 1;
    // ---- cell 1: K = 32 (x) + 128 (h1); B-frags from VGPRs ----
    #pragma unroll
    for (int rf = 0; rf < 4; ++rf) {
      int arow = rf * 16 + l15;
      s16x8 ax = *(const s16x8*)(smem + XT_OFF + xb * 4096 + swzx(arow, l16 * 16));
      s16x8 ah[4];
      #pragma unroll
      for (int kf = 0; kf < 4; ++kf)
        ah[kf] = *(const s16x8*)(smem + H1_OFF + swzh(arow, kf * 64 + l16 * 16));
      f32x4 aR  = {b_r,  b_r,  b_r,  b_r };
      f32x4 aZ  = {b_z,  b_z,  b_z,  b_z };
      f32x4 aCi = {b_ci, b_ci, b_ci, b_ci};
      f32x4 aCh = {b_ch, b_ch, b_ch, b_ch};
      aR  = __builtin_amdgcn_mfma_f32_16x16x32_bf16(ax, fw_ih1[0], aR, 0, 0, 0);
      aZ  = __builtin_amdgcn_mfma_f32_16x16x32_bf16(ax, fw_ih1[1], aZ, 0, 0, 0);
      aCi = __builtin_amdgcn_mfma_f32_16x16x32_bf16(ax, fw_ih1[2], aCi, 0, 0, 0);
      #pragma unroll
      for (int kf = 0; kf < 4; ++kf) {
        aR  = __builtin_amdgcn_mfma_f32_16x16x32_bf16(ah[kf], fw_hh1[kf][0], aR, 0, 0, 0);
        aZ  = __builtin_amdgcn_mfma_f32_16x16x32_bf16(ah[kf], fw_hh1[kf][1], aZ, 0, 0, 0);
        aCh = __builtin_amdgcn_mfma_f32_16x16x32_bf16(ah[kf], fw_hh1[kf][2], aCh, 0, 0, 0);
      }
      #pragma unroll
      for (int j = 0; j < 4; ++j) {
        float r = fsig(aR[j]);
        float z = fsig(aZ[j]);
        float c = ftanh(fmaf(r, aCh[j], aCi[j]));
        float h0 = fmaxf(fmaf(z, h1reg[rf][j] - c, c), 0.f);
        int row = rf * 16 + l16 * 4 + j;
        *(short*)(smem + H0_OFF + swzh(row, (hc0 + l15) << 1)) = f2bf(h0);
      }
    }
    __syncthreads();

    // ---- cell 2 (h==0): B-frags from LDS, shared across each rf pair ----
    float2 xv0 = make_float2(0.f, 0.f), xv1 = make_float2(0.f, 0.f);
    const bool do_stage = (t + 1 < TSTEPS);
    if (do_stage && skp < 14) {
      xv0 = *(const float2*)(x + (size_t)(n0 + srow) * 784 + (t + 1) * 28 + 2 * skp);
      xv1 = *(const float2*)(x + (size_t)(n0 + srow + 32) * 784 + (t + 1) * 28 + 2 * skp);
    }
    #pragma unroll
    for (int rfh = 0; rfh < 2; ++rfh) {
      const int r0 = rfh * 32 + l15;        // rows for rf = 2*rfh
      const int r1 = r0 + 16;               // rows for rf = 2*rfh+1
      f32x4 aR2[2], aZ2[2], aC2[2];
      #pragma unroll
      for (int p = 0; p < 2; ++p) {
        aR2[p] = (f32x4){c_r2, c_r2, c_r2, c_r2};
        aZ2[p] = (f32x4){c_z2, c_z2, c_z2, c_z2};
        aC2[p] = (f32x4){c_c2, c_c2, c_c2, c_c2};
      }
      #pragma unroll
      for (int kf = 0; kf < 4; ++kf) {
        s16x8 a0 = *(const s16x8*)(smem + H0_OFF + swzh(r0, kf * 64 + l16 * 16));
        s16x8 a1 = *(const s16x8*)(smem + H0_OFF + swzh(r1, kf * 64 + l16 * 16));
        const char* wb = smem + WI2_OFF + ((wv * 12 + kf * 3) << 10) + lane * 16;
        s16x8 b0 = *(const s16x8*)(wb);
        s16x8 b1 = *(const s16x8*)(wb + 1024);
        s16x8 b2 = *(const s16x8*)(wb + 2048);
        aR2[0] = __builtin_amdgcn_mfma_f32_16x16x32_bf16(a0, b0, aR2[0], 0, 0, 0);
        aR2[1] = __builtin_amdgcn_mfma_f32_16x16x32_bf16(a1, b0, aR2[1], 0, 0, 0);
        aZ2[0] = __builtin_amdgcn_mfma_f32_16x16x32_bf16(a0, b1, aZ2[0], 0, 0, 0);
        aZ2[1] = __builtin_amdgcn_mfma_f32_16x16x32_bf16(a1, b1, aZ2[1], 0, 0, 0);
        aC2[0] = __builtin_amdgcn_mfma_f32_16x16x32_bf16(a0, b2, aC2[0], 0, 0, 0);
        aC2[1] = __builtin_amdgcn_mfma_f32_16x16x32_bf16(a1, b2, aC2[1], 0, 0, 0);
      }
      #pragma unroll
      for (int p = 0; p < 2; ++p)
        #pragma unroll
        for (int j = 0; j < 4; ++j) {
          float r2 = fsig(aR2[p][j]);
          float z2 = fsig(aZ2[p][j]);
          float c2 = ftanh(fmaf(r2, c_hc2, aC2[p][j]));
          float h1n = c2 - z2 * c2;                 // (1-z2)*c2
          int rf = rfh * 2 + p;
          h1reg[rf][j] = h1n;
          int row = rf * 16 + l16 * 4 + j;
          *(short*)(smem + H1_OFF + swzh(row, (hc0 + l15) << 1)) = f2bf(h1n);
        }
    }
    if (do_stage) {
      *(unsigned int*)(smem + XT_OFF + (xb ^ 1) * 4096 + swzx(srow, skp * 4)) =
          pack2bf(xv0.x, xv0.y);
      *(unsigned int*)(smem + XT_OFF + (xb ^ 1) * 4096 + swzx(srow + 32, skp * 4)) =
          pack2bf(xv1.x, xv1.y);
    }
    __syncthreads();
  }

  // ---- final projection: out = h1 @ Wout^T + bout (fp32 h1 from regs) ----
  float* houtf = (float*)smem;   // [64][132] overlay = 33792 B
  #pragma unroll
  for (int rf = 0; rf < 4; ++rf)
    #pragma unroll
    for (int j = 0; j < 4; ++j) {
      int row = rf * 16 + l16 * 4 + j;
      houtf[row * 132 + hc0 + l15] = h1reg[rf][j];
    }
  __syncthreads();
  for (int task = tid; task < BN * 10; task += 512) {
    int row = task & 63;
    int o = task >> 6;
    const float* hp = houtf + row * 132;
    const float* wp = Wout + o * HID;
    float s = bout[o];
    #pragma unroll 8
    for (int j2 = 0; j2 < HID; ++j2) s = fmaf(hp[j2], wp[j2], s);
    out[(size_t)(n0 + row) * 10 + o] = s;
  }
}

extern "C" void kernel_launch(void* const* d_in, const int* in_sizes, int n_in,
                              void* d_out, int out_size, void* d_ws, size_t ws_size,
                              hipStream_t stream) {
  const float* x    = (const float*)d_in[0];
  const float* Wih1 = (const float*)d_in[1];
  const float* Whh1 = (const float*)d_in[2];
  const float* bih1 = (const float*)d_in[3];
  const float* bhh1 = (const float*)d_in[4];
  const float* Wih2 = (const float*)d_in[5];
  // d_in[6] = Whh2: multiplied by zero hidden state in the reference -> unused
  const float* bih2 = (const float*)d_in[7];
  const float* bhh2 = (const float*)d_in[8];
  const float* Wout = (const float*)d_in[9];
  const float* bout = (const float*)d_in[10];
  gru_kernel<<<NB / BN, 512, 0, stream>>>(x, Wih1, Whh1, bih1, bhh1,
                                          Wih2, bih2, bhh2, Wout, bout,
                                          (float*)d_out);
}